// Round 7
// baseline (34.352 us; speedup 1.0000x reference)
//
#include <hip/hip_runtime.h>
#include <cmath>

#define PH 7
#define PW 7
#define FH 64
#define FW 64
#define CC 512
#define SCALE 0.0625f

typedef float f32x4 __attribute__((ext_vector_type(4)));

static __device__ __forceinline__ f32x4 vmax4(f32x4 a, f32x4 b) {
    f32x4 r;
    r.x = fmaxf(a.x, b.x); r.y = fmaxf(a.y, b.y);
    r.z = fmaxf(a.z, b.z); r.w = fmaxf(a.w, b.w);
    return r;
}

// ---------------------------------------------------------------------------
// Kernel 1: counting sort of ROIs by feature-space start row (64 buckets) AND
// per-ROI geometry precompute. Output: geo[sorted_slot] = float4
//   {bin_h, bin_w, bitcast(n | sh<<10 | sw<<17 | bidx<<24), 0}
// so the pool kernel's prologue is a single 16B broadcast load.
// Bin sizes use the XLA reciprocal-multiply form roi/7 -> roi * fl32(1/7)
// (AlgebraicSimplifier rewrite — proven bit-exact in round 3).
// ---------------------------------------------------------------------------
__global__ __launch_bounds__(512) void sort_rois_kernel(
        const float* __restrict__ rois, int N, float4* __restrict__ geo) {
    __shared__ int base[64];
    __shared__ int cur[64];
    int t = threadIdx.x;
    if (t < 64) { base[t] = 0; cur[t] = 0; }
    __syncthreads();
    int b = -1, packed = 0;
    float bh = 0.f, bw = 0.f;
    if (t < N) {
        const float* r = rois + (size_t)t * 5;
        int bidx = (int)r[0];
        // jnp.round == round-half-to-even == rintf (RNE); x*0.0625 exact
        int sw = (int)rintf(r[1] * SCALE);
        int sh = (int)rintf(r[2] * SCALE);
        int ew = (int)rintf(r[3] * SCALE);
        int eh = (int)rintf(r[4] * SCALE);
        bh = fmaxf((float)(eh - sh + 1), 1.0f) * (1.0f / 7.0f);
        bw = fmaxf((float)(ew - sw + 1), 1.0f) * (1.0f / 7.0f);
        packed = t | (sh << 10) | (sw << 17) | (bidx << 24);  // sh,sw in [0,64]
        b = min(max(sh, 0), FH - 1);
        atomicAdd(&base[b], 1);
    }
    __syncthreads();
    if (t == 0) {
        int acc = 0;
        for (int i = 0; i < 64; ++i) { int c = base[i]; base[i] = acc; acc += c; }
    }
    __syncthreads();
    if (t < N) {
        int pos = base[b] + atomicAdd(&cur[b], 1);
        float4 g;
        g.x = bh; g.y = bw; g.z = __int_as_float(packed); g.w = 0.f;
        geo[pos] = g;
    }
}

// ---------------------------------------------------------------------------
// Kernel 2: Caffe ROI max-pool. One 64-lane wave per bin (sorted order, XCD-
// chunked swizzle for per-XCD L2 banding — FETCH 112->26 MB proven round 4).
// Lane owns channels [l*4,+4) and [256+l*4,+4).
//
// Round-7 changes vs round 6:
//  * geometry from precomputed geo[] (1 broadcast load, no perm->roi chain)
//  * window walker fully SCALARIZED via readfirstlane: offsets/counters in
//    SGPRs, loads become s[base]+voff with the +256ch load as offset:1024
//  * cell count padded to a multiple of 4 by substituting cell-0's offset
//    (max is idempotent -> duplicate read is free): no 1-deep tail loop,
//    always 8 independent dwordx4 loads in flight.
// ---------------------------------------------------------------------------
__global__ __launch_bounds__(256) void roi_pool_kernel(
        const float* __restrict__ feat,
        const float4* __restrict__ geo,
        float* __restrict__ out,
        int nBins) {
    // bijective XCD-chunk swizzle (HW: XCD = blockIdx % 8)
    int p = blockIdx.x;
    int nwg = gridDim.x;
    int q = nwg >> 3, rr = nwg & 7;
    int xcd = p & 7, o = p >> 3;
    int L = (xcd < rr ? xcd * (q + 1) : rr * (q + 1) + (xcd - rr) * q) + o;

    int tid = L * 256 + (int)threadIdx.x;
    int bin = tid >> 6;          // one wave per bin (sorted order)
    int lane = tid & 63;
    if (bin >= nBins) return;

    int s   = bin / (PH * PW);   // sorted roi slot
    int rem = bin - s * (PH * PW);
    int ph  = rem / PW;
    int pw  = rem - ph * PW;

    float4 g = geo[s];
    float bh = g.x, bw = g.y;
    int packed = __float_as_int(g.z);
    int n    = packed & 1023;
    int sh   = (packed >> 10) & 127;
    int sw   = (packed >> 17) & 127;
    int bidx = (packed >> 24) & 255;

    int hstart = min(max((int)floorf((float)ph * bh) + sh, 0), FH);
    int hend   = min(max((int)ceilf((float)(ph + 1) * bh) + sh, 0), FH);
    int wstart = min(max((int)floorf((float)pw * bw) + sw, 0), FW);
    int wend   = min(max((int)ceilf((float)(pw + 1) * bw) + sw, 0), FW);

    int Wn = wend - wstart;
    int Hn = hend - hstart;
    bool empty = (Hn <= 0) || (Wn <= 0);

    f32x4 mxA = { -INFINITY, -INFINITY, -INFINITY, -INFINITY };
    f32x4 mxB = mxA;

    if (!empty) {
        // scalarize the walker: all wave-uniform values -> SGPRs
        unsigned cells = (unsigned)__builtin_amdgcn_readfirstlane(Hn * Wn);
        unsigned Wu    = (unsigned)__builtin_amdgcn_readfirstlane(Wn);
        unsigned wrap  = (unsigned)__builtin_amdgcn_readfirstlane((FW - Wn + 1) * CC);
        unsigned off0  = (unsigned)__builtin_amdgcn_readfirstlane(
            (bidx * FH * FW + hstart * FW + wstart) * CC);

        const float* fb = feat + off0;       // SGPR base
        unsigned vo = (unsigned)lane * 4;    // per-lane float offset (VGPR)

        unsigned soff = 0;                   // scalar cell offset (floats)
        unsigned cw = Wu;                    // cols left in current row
        unsigned c = 0;
        unsigned quads = (cells + 3) >> 2;

#define ADV() do { if (--cw == 0) { soff += wrap; cw = Wu; } else soff += CC; } while (0)

        for (; quads; --quads) {
            unsigned o0 = soff;                          ADV();
            unsigned o1 = (c + 1 < cells) ? soff : 0u;   ADV();
            unsigned o2 = (c + 2 < cells) ? soff : 0u;   ADV();
            unsigned o3 = (c + 3 < cells) ? soff : 0u;   ADV();
            c += 4;
            const float* p0 = fb + o0;
            const float* p1 = fb + o1;
            const float* p2 = fb + o2;
            const float* p3 = fb + o3;
            f32x4 a0 = *(const f32x4*)(p0 + vo);  f32x4 b0 = *(const f32x4*)(p0 + vo + 256);
            f32x4 a1 = *(const f32x4*)(p1 + vo);  f32x4 b1 = *(const f32x4*)(p1 + vo + 256);
            f32x4 a2 = *(const f32x4*)(p2 + vo);  f32x4 b2 = *(const f32x4*)(p2 + vo + 256);
            f32x4 a3 = *(const f32x4*)(p3 + vo);  f32x4 b3 = *(const f32x4*)(p3 + vo + 256);
            a0 = vmax4(a0, a1); a2 = vmax4(a2, a3);
            b0 = vmax4(b0, b1); b2 = vmax4(b2, b3);
            mxA = vmax4(mxA, vmax4(a0, a2));
            mxB = vmax4(mxB, vmax4(b0, b2));
        }
#undef ADV
    } else {
        mxA = (f32x4){0.f, 0.f, 0.f, 0.f};
        mxB = mxA;
    }

    float* op = out + ((size_t)n * (PH * PW) + rem) * CC + (size_t)lane * 4;
    __builtin_nontemporal_store(mxA, (f32x4*)op);
    __builtin_nontemporal_store(mxB, (f32x4*)(op + 256));
}

extern "C" void kernel_launch(void* const* d_in, const int* in_sizes, int n_in,
                              void* d_out, int out_size, void* d_ws, size_t ws_size,
                              hipStream_t stream) {
    const float* feat = (const float*)d_in[0];
    const float* rois = (const float*)d_in[1];
    float* out = (float*)d_out;
    float4* geo = (float4*)d_ws;           // 512 * 16B = 8KB scratch

    int N = in_sizes[1] / 5;               // 512 rois
    sort_rois_kernel<<<1, 512, 0, stream>>>(rois, N, geo);

    int nBins = N * PH * PW;               // 25088
    int totalThreads = nBins * 64;         // one wave per bin
    int block = 256;
    int grid = (totalThreads + block - 1) / block;
    roi_pool_kernel<<<grid, block, 0, stream>>>(feat, geo, out, nBins);
}